// Round 11
// baseline (367.847 us; speedup 1.0000x reference)
//
#include <hip/hip_runtime.h>
#include <stdint.h>

#define M_DIM 8192
#define N_DIM 8192
#define K_DIM 1024

typedef int int4v __attribute__((ext_vector_type(4)));

// ---- async global->LDS, 16B per lane ----
__device__ __forceinline__ void gload16(const char* g, char* l) {
    __builtin_amdgcn_global_load_lds(
        (__attribute__((address_space(1))) void*)(void*)const_cast<char*>(g),
        (__attribute__((address_space(3))) void*)l,
        16, 0, 0);
}

__device__ __forceinline__ int sat8(int v) {
    v = v > 127 ? 127 : v;
    v = v < -128 ? -128 : v;
    return v;
}

// ---- fused pack into TILE-MAJOR layout, T2 swizzle baked at store time ----
// Layout: [blk128][K64-slice(16)][row(128)][64B], 128KB per 128-row block.
// Stored 16B-chunk sc of (row, slice) holds logical chunk sc^((row>>1)&3).
// => GEMM staging reads are fully linear/contiguous (1KB per wave-instr).
__global__ __launch_bounds__(256) void pack_ab_kernel(const int* __restrict__ a,
                                                      const int* __restrict__ b,
                                                      char* __restrict__ outA,
                                                      char* __restrict__ outB) {
    __shared__ char tile[64][68];               // used by B-blocks only
    const int t = threadIdx.x;
    if (blockIdx.x < 8192) {
        // pack a: block bx handles row m=bx (1024 int32 -> 1024 int8)
        const int m   = blockIdx.x;
        const int row = m & 127;
        const int xr  = (row >> 1) & 3;          // baked swizzle constant
        const int4 v  = ((const int4*)a)[m * 256 + t];
        const int pk  = (v.x & 0xff) | ((v.y & 0xff) << 8) |
                        ((v.z & 0xff) << 16) | ((v.w & 0xff) << 24);
        const int k     = t * 4;
        const int slice = k >> 6;                // t>>4
        const int sc    = ((k >> 4) & 3) ^ xr;
        *(int*)&outA[(size_t)(m >> 7) * 131072 + slice * 8192 + row * 64 +
                     sc * 16 + (k & 15)] = pk;
        return;
    }
    // pack b: int32 [K][N] -> int8 tile-major [N-blk][K64][n-row][64B] (transpose)
    const int bx = blockIdx.x - 8192;           // 0..2047
    const int n0 = (bx & 127) * 64;
    const int k0 = (bx >> 7) * 64;
    const int tr  = t >> 4;                     // 0..15
    const int tc4 = (t & 15) << 2;              // 0,4,..,60
#pragma unroll
    for (int j = 0; j < 4; ++j) {
        int row = tr + j * 16;                  // k within tile
        int4 v = *(const int4*)&b[(size_t)(k0 + row) * N_DIM + n0 + tc4];
        tile[row][tc4 + 0] = (char)v.x;
        tile[row][tc4 + 1] = (char)v.y;
        tile[row][tc4 + 2] = (char)v.z;
        tile[row][tc4 + 3] = (char)v.w;
    }
    __syncthreads();
    const int slice = k0 >> 6;
#pragma unroll
    for (int j = 0; j < 4; ++j) {
        int n = tr + j * 16;                    // n within tile
        int pk = (tile[tc4 + 0][n] & 0xff) |
                 ((tile[tc4 + 1][n] & 0xff) << 8) |
                 ((tile[tc4 + 2][n] & 0xff) << 16) |
                 ((tile[tc4 + 3][n] & 0xff) << 24);
        const int ng  = n0 + n;
        const int row = ng & 127;
        const int sc  = (tc4 >> 4) ^ ((row >> 1) & 3);
        *(int*)&outB[(size_t)(ng >> 7) * 131072 + slice * 8192 + row * 64 +
                     sc * 16 + (tc4 & 15)] = pk;
    }
}

// ---- GEMM: 256x256, BK=64, 8 waves, TRUE 8-phase interleave (m201 port) ----
// R10 fit: total = ~265us fixed + gemm; gemm ~100us = 35% of i8 peak = the
// documented m97-structure ceiling, invariant to every single-lever change
// (8 nulls). Only verified escape: the 8-phase fine interleave (per-phase
// ds_read || 1 gload || MFMA cluster, counted vmcnt NEVER 0 in-loop; coarse
// splits (R8) and shallow loops (R1, BK=128 -> 4 iters) demonstrably don't
// work). This is R1 corrected: BK=64 -> 16 K-tiles -> 8 full iterations;
// tile-major LINEAR staging (R10 pack; R9 showed scattered segments double
// cost); 4-slot ring, 1 gload/phase, vmcnt(4) at phases 3 & 7 only.
// Ledger (verified): iter j computes tiles 2j,2j+1 (slots (2j)&3,(2j+1)&3),
// stages 2j+2 (phases 0-3) and 2j+3 (phases 4-7) into the OTHER two slots;
// vmcnt(4)@ph3 retires tile 2j+3's prerequisites... concretely each wait
// leaves exactly the 4 newest loads in flight and retires the tile consumed
// 4 phases later. Slots read vs DMA-written never alias within an iter.
__global__ __launch_bounds__(512, 2) void gemm_i8_kernel(const char* __restrict__ A8,
                                                         const char* __restrict__ B8,
                                                         int* __restrict__ C) {
    // smem[0:64K) = As[4][256][64] ring; smem[64K:128K) = Bs ring.
    // Epilogue reuses [0, 68K) as 8 wave-private 32x68-int regions.
    __shared__ __align__(16) char smem[131072];

    const int t    = threadIdx.x;
    const int bn   = blockIdx.x;
    const int bm   = blockIdx.y;
    const int lane = t & 63;
    const int wave = t >> 6;
    const int wm   = wave >> 2;                  // 0..1 : 128 output rows
    const int wn   = wave & 3;                   // 0..3 : 64 output cols
    const int quad = lane >> 4;
    const int l16  = lane & 15;
    const int f16  = t * 16;                     // linear stage offset 0..8191

    const char* aT0 = A8 + (size_t)(2 * bm) * 131072;      // rows 0-127
    const char* aT1 = aT0 + 131072;                        // rows 128-255
    const char* bT0 = B8 + (size_t)(2 * bn) * 131072;
    const char* bT1 = bT0 + 131072;

    // swizzled read chunk (per-lane constant; pack baked sc^((row>>1)&3))
    const int laneByte = ((quad ^ ((l16 >> 1) & 3)) << 4);
    const int aRowByte = (wm * 128 + l16) * 64 + laneByte; // + mi*1024
    const int bRowByte = (wn * 64 + l16) * 64 + laneByte;  // + ni*1024

    int4v acc[8][4] = {};
    int4v bf[4];

#define STG_A0(T,S) gload16(aT0 + (T)*8192 + f16, smem + (S)*16384 + f16)
#define STG_A1(T,S) gload16(aT1 + (T)*8192 + f16, smem + (S)*16384 + 8192 + f16)
#define STG_B0(T,S) gload16(bT0 + (T)*8192 + f16, smem + 65536 + (S)*16384 + f16)
#define STG_B1(T,S) gload16(bT1 + (T)*8192 + f16, smem + 65536 + (S)*16384 + 8192 + f16)

#define PHASE(SLOT, MIH, LOADB, STG, VMW) do {                                      \
    int4v af0 = *(const int4v*)&smem[(SLOT)*16384 + aRowByte + ((MIH)*2+0)*1024];   \
    int4v af1 = *(const int4v*)&smem[(SLOT)*16384 + aRowByte + ((MIH)*2+1)*1024];   \
    if (LOADB) {                                                                    \
        bf[0] = *(const int4v*)&smem[65536 + (SLOT)*16384 + bRowByte + 0*1024];     \
        bf[1] = *(const int4v*)&smem[65536 + (SLOT)*16384 + bRowByte + 1*1024];     \
        bf[2] = *(const int4v*)&smem[65536 + (SLOT)*16384 + bRowByte + 2*1024];     \
        bf[3] = *(const int4v*)&smem[65536 + (SLOT)*16384 + bRowByte + 3*1024];     \
    }                                                                               \
    STG;                                                                            \
    __builtin_amdgcn_s_barrier();                                                   \
    asm volatile("s_waitcnt lgkmcnt(0)" ::: "memory");                              \
    __builtin_amdgcn_sched_barrier(0);  /* rule 18 */                               \
    __builtin_amdgcn_s_setprio(1);                                                  \
    _Pragma("unroll")                                                               \
    for (int ni = 0; ni < 4; ++ni) {                                                \
        acc[(MIH)*2+0][ni] = __builtin_amdgcn_mfma_i32_16x16x64_i8(                 \
            af0, bf[ni], acc[(MIH)*2+0][ni], 0, 0, 0);                              \
        acc[(MIH)*2+1][ni] = __builtin_amdgcn_mfma_i32_16x16x64_i8(                 \
            af1, bf[ni], acc[(MIH)*2+1][ni], 0, 0, 0);                              \
    }                                                                               \
    __builtin_amdgcn_s_setprio(0);                                                  \
    if (VMW) asm volatile("s_waitcnt vmcnt(4)" ::: "memory");                       \
    __builtin_amdgcn_s_barrier();                                                   \
} while (0)

    // prologue: tiles 0,1 fully staged (8 loads); retire tile 0, keep tile 1
    STG_A0(0, 0); STG_A1(0, 0); STG_B0(0, 0); STG_B1(0, 0);
    STG_A0(1, 1); STG_A1(1, 1); STG_B0(1, 1); STG_B1(1, 1);
    asm volatile("s_waitcnt vmcnt(4)" ::: "memory");
    __builtin_amdgcn_s_barrier();
    __builtin_amdgcn_sched_barrier(0);

#pragma unroll 2
    for (int j = 0; j < 8; ++j) {
        const int s0 = (2 * j) & 3;
        const int s1 = (2 * j + 1) & 3;
        const int su0 = (2 * j + 2) & 3;
        const int su1 = (2 * j + 3) & 3;
        const int u0 = (j < 7) ? 2 * j + 2 : 15;   // tail: redundant L2-hot loads
        const int u1 = (j < 7) ? 2 * j + 3 : 15;

        PHASE(s0, 0, 1, STG_A0(u0, su0), 0);
        PHASE(s0, 1, 0, STG_A1(u0, su0), 0);
        PHASE(s0, 2, 0, STG_B0(u0, su0), 0);
        PHASE(s0, 3, 0, STG_B1(u0, su0), 1);   // retires tile 2j+3's feed
        PHASE(s1, 0, 1, STG_A0(u1, su1), 0);
        PHASE(s1, 1, 0, STG_A1(u1, su1), 0);
        PHASE(s1, 2, 0, STG_B0(u1, su1), 0);
        PHASE(s1, 3, 0, STG_B1(u1, su1), 1);   // retires tile 2j+2 for next iter
    }
#undef PHASE
#undef STG_A0
#undef STG_A1
#undef STG_B0
#undef STG_B1

    // drain redundant tail stages, then repurpose LDS for the epilogue
    asm volatile("s_waitcnt vmcnt(0)" ::: "memory");
    __builtin_amdgcn_s_barrier();

    // epilogue (verified R8): acc (col=l16, row=4*quad+reg) -> per-wave LDS
    // transpose region (32 rows x 68-int padded) -> dwordx4 stores.
    int* lw = (int*)(smem + wave * 8704);        // 8 x 8704 B = 68 KiB
    const int mBase = bm * 256 + wm * 128;
    const int nW    = bn * 256 + wn * 64;
#pragma unroll
    for (int rnd = 0; rnd < 4; ++rnd) {          // 32 output rows per round
#pragma unroll
        for (int mh = 0; mh < 2; ++mh) {         // mi = rnd*2 + mh
            const int mi = rnd * 2 + mh;
#pragma unroll
            for (int ni = 0; ni < 4; ++ni)
#pragma unroll
                for (int r = 0; r < 4; ++r)
                    lw[(mh * 16 + quad * 4 + r) * 68 + ni * 16 + l16] =
                        sat8(acc[mi][ni][r]);
        }
        // same-wave DS ordering: compiler inserts lgkmcnt before dependent reads
#pragma unroll
        for (int rr = 0; rr < 8; ++rr) {
            const int R = rr * 4 + quad;         // local row 0..31
            const int4v v = *(const int4v*)&lw[R * 68 + l16 * 4];
            *(int4v*)&C[(size_t)(mBase + rnd * 32 + R) * N_DIM + nW + l16 * 4] = v;
        }
        // next round's writes ordered after reads by in-order per-wave DS pipe
    }
}

// ---- fallback (only if ws_size < 16MB): direct int32 GEMM, slow but correct ----
__global__ __launch_bounds__(256) void gemm_naive_kernel(const int* __restrict__ a,
                                                         const int* __restrict__ b,
                                                         int* __restrict__ C) {
    const int col = blockIdx.x * 256 + threadIdx.x;
    const int row = blockIdx.y;
    int acc = 0;
    for (int k = 0; k < K_DIM; ++k)
        acc += a[(size_t)row * K_DIM + k] * b[(size_t)k * N_DIM + col];
    C[(size_t)row * N_DIM + col] = sat8(acc);
}

extern "C" void kernel_launch(void* const* d_in, const int* in_sizes, int n_in,
                              void* d_out, int out_size, void* d_ws, size_t ws_size,
                              hipStream_t stream) {
    const int* a = (const int*)d_in[0];
    const int* b = (const int*)d_in[1];
    // alpha_row (d_in[2]) / alpha_col (d_in[3]) are unused in this variant.
    int* out = (int*)d_out;

    const size_t needed = 2 * (size_t)M_DIM * K_DIM;   // 16 MB packed operands
    if (ws_size < needed) {
        gemm_naive_kernel<<<dim3(N_DIM / 256, M_DIM), 256, 0, stream>>>(a, b, out);
        return;
    }

    char* A8 = (char*)d_ws;                          // 8 MB
    char* B8 = A8 + (size_t)M_DIM * K_DIM;           // 8 MB

    pack_ab_kernel<<<8192 + 2048, 256, 0, stream>>>(a, b, A8, B8);
    gemm_i8_kernel<<<dim3(N_DIM / 256, M_DIM / 256), 512, 0, stream>>>(A8, B8, out);
}